// Round 3
// baseline (655.655 us; speedup 1.0000x reference)
//
#include <hip/hip_runtime.h>
#include <hip/hip_bf16.h>
#include <math.h>

// Problem constants
#define B_   16
#define IN_  1024
#define H_   1024
#define DK_  1024
#define D1_  4096
#define LR_  0.01f

typedef float vf4 __attribute__((ext_vector_type(4)));

// ---------------------------------------------------------------------------
// Shared inner loop: wave computes dot(W row, V[b] row) for b in [0,16),
// V tile staged in LDS. K multiple of 256. Butterfly (xor) reduction so the
// final sum for each b is present in ALL lanes of the wave.
// ---------------------------------------------------------------------------
#define ROWGEMM_BODY(WPTR, VPTR, K)                                         \
  __shared__ float vtile[16][256];                                          \
  const int tid  = threadIdx.x;                                             \
  const int lane = tid & 63;                                                \
  float acc[16];                                                            \
  _Pragma("unroll")                                                         \
  for (int b = 0; b < 16; ++b) acc[b] = 0.f;                                \
  for (int k0 = 0; k0 < (K); k0 += 256) {                                   \
    __syncthreads();                                                        \
    _Pragma("unroll")                                                       \
    for (int idx = tid; idx < 1024; idx += 256) {                           \
      int bb = idx >> 6;                                                    \
      int cc = (idx & 63) << 2;                                             \
      *(vf4*)&vtile[bb][cc] = *(const vf4*)((VPTR) + (size_t)bb * (K) + k0 + cc); \
    }                                                                       \
    __syncthreads();                                                        \
    const int c = lane << 2;                                                \
    vf4 w4 = *(const vf4*)((WPTR) + k0 + c);                                \
    _Pragma("unroll")                                                       \
    for (int b = 0; b < 16; ++b) {                                          \
      vf4 v4 = *(const vf4*)&vtile[b][c];                                   \
      acc[b] += w4.x * v4.x + w4.y * v4.y + w4.z * v4.z + w4.w * v4.w;      \
    }                                                                       \
  }                                                                         \
  _Pragma("unroll")                                                         \
  for (int b = 0; b < 16; ++b) {                                            \
    float a = acc[b];                                                       \
    _Pragma("unroll")                                                       \
    for (int m = 32; m; m >>= 1) a += __shfl_xor(a, m, 64);                 \
    acc[b] = a;                                                             \
  }

// ---------------------------------------------------------------------------
// Fused projections: rows [0,1024) -> kt from W_k, rows [1024,2048) -> vt from W_v
// grid = 512 blocks
// ---------------------------------------------------------------------------
__global__ __launch_bounds__(256) void proj_kernel(
    const float* __restrict__ W_k, const float* __restrict__ W_v,
    const float* __restrict__ x, float* __restrict__ kt, float* __restrict__ vt) {
  const int grow = blockIdx.x * 4 + (threadIdx.x >> 6);
  const int row  = grow & 1023;
  const float* wrow = (grow < 1024 ? W_k : W_v) + (size_t)row * 1024;
  float* out = (grow < 1024) ? kt : vt;
  ROWGEMM_BODY(wrow, x, 1024)
  if (lane == 0) {
#pragma unroll
    for (int b = 0; b < 16; ++b) out[b * 1024 + row] = acc[b];
  }
}

// ---------------------------------------------------------------------------
// z = W0 @ kt with fused exact-GELU epilogue: writes g and gp directly.
// grid = 1024 blocks (rows of 4096)
// ---------------------------------------------------------------------------
__global__ __launch_bounds__(256) void z_gelu_kernel(
    const float* __restrict__ W0, const float* __restrict__ kt,
    float* __restrict__ g, float* __restrict__ gp) {
  const int row = blockIdx.x * 4 + (threadIdx.x >> 6);
  const float* wrow = W0 + (size_t)row * 1024;
  ROWGEMM_BODY(wrow, kt, 1024)
  if (lane == 0) {
#pragma unroll
    for (int b = 0; b < 16; ++b) {
      const float x   = acc[b];
      const float cdf = 0.5f * (1.f + erff(x * 0.70710678118654752f));
      g[b * 4096 + row]  = x * cdf;
      gp[b * 4096 + row] = cdf + x * 0.39894228040143268f * expf(-0.5f * x * x);
    }
  }
}

// ---------------------------------------------------------------------------
// h = W1 @ g with fused dh epilogue: dh = (h - vt)/1024. grid = 256 blocks.
// ---------------------------------------------------------------------------
__global__ __launch_bounds__(256) void h_dh_kernel(
    const float* __restrict__ W1, const float* __restrict__ g,
    const float* __restrict__ vt, float* __restrict__ h, float* __restrict__ dh) {
  const int row = blockIdx.x * 4 + (threadIdx.x >> 6);
  const float* wrow = W1 + (size_t)row * 4096;
  ROWGEMM_BODY(wrow, g, 4096)
  if (lane == 0) {
#pragma unroll
    for (int b = 0; b < 16; ++b) {
      const float hv = acc[b];
      h[b * 1024 + row]  = hv;
      dh[b * 1024 + row] = (hv - vt[b * 1024 + row]) * (1.0f / 1024.0f);
    }
  }
}

// ---------------------------------------------------------------------------
// dg partials: partial[s][b][j] = sum_{i in chunk s} W1[i][j]*dh[b][i]
// grid = (16 j-tiles, 16 i-chunks of 64 rows), block = 256
// ---------------------------------------------------------------------------
__global__ __launch_bounds__(256) void colgemm_partial(
    const float* __restrict__ W1, const float* __restrict__ dh,
    float* __restrict__ partial) {
  __shared__ float dhs[16][64];
  const int t  = threadIdx.x;
  const int j  = blockIdx.x * 256 + t;
  const int i0 = blockIdx.y * 64;
#pragma unroll
  for (int idx = t; idx < 16 * 64; idx += 256) {
    int b = idx >> 6, c = idx & 63;
    dhs[b][c] = dh[b * 1024 + i0 + c];
  }
  __syncthreads();
  float acc[16];
#pragma unroll
  for (int b = 0; b < 16; ++b) acc[b] = 0.f;
  for (int c = 0; c < 64; ++c) {
    float w = W1[(size_t)(i0 + c) * D1_ + j];   // coalesced across threads
#pragma unroll
    for (int b = 0; b < 16; ++b) acc[b] += w * dhs[b][c];
  }
  const int s = blockIdx.y;
#pragma unroll
  for (int b = 0; b < 16; ++b)
    partial[((size_t)s * 16 + b) * D1_ + j] = acc[b];
}

// ---------------------------------------------------------------------------
// Mega-kernel: all 537 MB of streaming writes + output projection in ONE
// dispatch (2304 blocks):
//   blocks [0,1024):    W0_new, 4 rows/block; dz computed INLINE from
//                       partial+gp (replaces reduce_dz kernel).
//   blocks [1024,2048): W1_new, 1 row/block (4 col-chunks in regs).
//   blocks [2048,2304): output = h @ W_o^T (rowgemm).
// ---------------------------------------------------------------------------
__global__ __launch_bounds__(256) void mega_kernel(
    const float* __restrict__ W0, const float* __restrict__ partial,
    const float* __restrict__ gp, const float* __restrict__ kt,
    const float* __restrict__ W1, const float* __restrict__ dh,
    const float* __restrict__ g,
    const float* __restrict__ W_o, const float* __restrict__ h,
    float* __restrict__ out0, float* __restrict__ out1, float* __restrict__ out2) {
  const int blk = blockIdx.x;
  const int t   = threadIdx.x;
  if (blk < 1024) {
    // ---- W0 update, rows i0..i0+3, dz inline ----
    __shared__ float dzs[16][4];
    const int i0 = blk << 2;
    {
      const int b = t >> 4;    // [0,16)
      const int s = t & 15;    // [0,16)
#pragma unroll
      for (int r = 0; r < 4; ++r) {
        float p = partial[(size_t)(s * 16 + b) * 4096 + i0 + r];
#pragma unroll
        for (int m = 8; m; m >>= 1) p += __shfl_xor(p, m, 16);
        if (s == 0) dzs[b][r] = p * gp[(b << 12) + i0 + r];
      }
    }
    __syncthreads();
    const int j = t << 2;
    vf4 w[4];
#pragma unroll
    for (int r = 0; r < 4; ++r)
      w[r] = *(const vf4*)(W0 + ((size_t)(i0 + r) << 10) + j);
#pragma unroll
    for (int b = 0; b < 16; ++b) {
      const vf4 k4 = *(const vf4*)(kt + (b << 10) + j);
      float* ob = out1 + ((size_t)b << 22);
#pragma unroll
      for (int r = 0; r < 4; ++r) {
        const float d = LR_ * dzs[b][r];
        *(vf4*)(ob + ((size_t)(i0 + r) << 10) + j) = w[r] - d * k4;
      }
    }
  } else if (blk < 2048) {
    // ---- W1 update, 1 row (4096 floats) ----
    const int i = blk - 1024;
    vf4 w[4];
#pragma unroll
    for (int c = 0; c < 4; ++c)
      w[c] = *(const vf4*)(W1 + ((size_t)i << 12) + (c << 10) + (t << 2));
#pragma unroll
    for (int b = 0; b < 16; ++b) {
      const float d = LR_ * dh[(b << 10) + i];                 // wave-uniform
      float* ob = out2 + ((size_t)b << 22) + ((size_t)i << 12);
      const float* gb = g + (b << 12);
#pragma unroll
      for (int c = 0; c < 4; ++c) {
        const vf4 g4 = *(const vf4*)(gb + (c << 10) + (t << 2));
        *(vf4*)(ob + (c << 10) + (t << 2)) = w[c] - d * g4;
      }
    }
  } else {
    // ---- output projection: out0[b][row] = dot(W_o[row], h[b]) ----
    const int row = (blk - 2048) * 4 + (t >> 6);
    const float* wrow = W_o + (size_t)row * 1024;
    ROWGEMM_BODY(wrow, h, 1024)
    if (lane == 0) {
#pragma unroll
      for (int b = 0; b < 16; ++b) out0[b * 1024 + row] = acc[b];
    }
  }
}

extern "C" void kernel_launch(void* const* d_in, const int* in_sizes, int n_in,
                              void* d_out, int out_size, void* d_ws, size_t ws_size,
                              hipStream_t stream) {
  const float* x_t = (const float*)d_in[0];  // [16,1024]
  const float* W_k = (const float*)d_in[1];  // [1024,1024]
  const float* W_v = (const float*)d_in[2];  // [1024,1024]
  const float* W_o = (const float*)d_in[3];  // [1024,1024]
  const float* W0  = (const float*)d_in[4];  // [4096,1024]
  const float* W1  = (const float*)d_in[5];  // [1024,4096]

  float* out0 = (float*)d_out;               // output [16,1024]
  float* out1 = out0 + 16384;                // W0_new [16,4096,1024]
  float* out2 = out1 + (size_t)16 * 4096 * 1024;  // W1_new [16,1024,4096]

  // workspace layout (floats)
  float* ws      = (float*)d_ws;
  float* kt      = ws;                  // 16*1024
  float* vt      = kt + 16384;          // 16*1024
  float* g       = vt + 16384;          // 16*4096
  float* gp      = g + 65536;           // 16*4096
  float* h       = gp + 65536;          // 16*1024
  float* dh      = h + 16384;           // 16*1024
  float* partial = dh + 16384;          // 16*16*4096

  // projections: k_t = x @ W_k^T, v_t = x @ W_v^T  (one dispatch)
  proj_kernel<<<512, 256, 0, stream>>>(W_k, W_v, x_t, kt, vt);
  // forward MLP with fused GELU
  z_gelu_kernel<<<1024, 256, 0, stream>>>(W0, kt, g, gp);
  // h = W1 @ g with fused dh
  h_dh_kernel<<<256, 256, 0, stream>>>(W1, g, vt, h, dh);
  // gradient partials (dz finished inline in mega_kernel)
  colgemm_partial<<<dim3(16, 16), 256, 0, stream>>>(W1, dh, partial);
  // all streaming writes + output projection
  mega_kernel<<<2304, 256, 0, stream>>>(W0, partial, gp, kt,
                                        W1, dh, g, W_o, h,
                                        out0, out1, out2);
}